// Round 9
// baseline (1249.568 us; speedup 1.0000x reference)
//
#include <hip/hip_runtime.h>

#define NUSERS 50000
#define NITEMS 20000
#define NEDGES 400000

typedef _Float16 f16;
typedef __attribute__((ext_vector_type(8))) _Float16 f16x8;
typedef __attribute__((ext_vector_type(4))) _Float16 f16x4;
typedef __attribute__((ext_vector_type(2))) _Float16 f16x2;
typedef __attribute__((ext_vector_type(4))) float f32x4;

// ---------- prep: weight transpose->f16 + folded el/er projections, both relations ----------
__global__ void prep_k(const float* __restrict__ Wa, const float* __restrict__ Aa,
                       f16* __restrict__ Bta, float* __restrict__ efa,
                       const float* __restrict__ Wb, const float* __restrict__ Ab,
                       f16* __restrict__ Btb, float* __restrict__ efb,
                       int K, int Nw, int dh) {
  int t = blockIdx.x * blockDim.x + threadIdx.x;
  int half = K * Nw;
  if (t >= 2 * half) return;
  const float* W = (t < half) ? Wa : Wb;
  const float* A = (t < half) ? Aa : Ab;
  f16* Bt = (t < half) ? Bta : Btb;
  float* ef = (t < half) ? efa : efb;
  int t2 = (t < half) ? t : t - half;
  int n = t2 / K, k = t2 - n * K;
  Bt[t2] = (f16)W[(long)k * Nw + n];
  if (t2 < K * 8) {
    int j = t2 / (K * 4);
    int r = t2 - j * K * 4;
    int h = r / K, f = r - h * K;
    const float* Aj = A + j * Nw;   // A[j], shape [4,dh], Nw = 4*dh
    float s = 0.f;
    for (int d = 0; d < dh; ++d) s += W[f * Nw + h * dh + d] * Aj[h * dh + d];
    ef[j * 4 * K + h * K + f] = s;
  }
}

// ---------- f16 MFMA GEMM, user+item fused: C = A[M,K] @ Bt[N,K]^T ----------
__global__ __launch_bounds__(256) void hgemm2_k(const f16* __restrict__ Aa, const f16* __restrict__ Bta,
                                                f16* __restrict__ Ca, int Ma, int gya,
                                                const f16* __restrict__ Ab, const f16* __restrict__ Btb,
                                                f16* __restrict__ Cb, int Mb,
                                                int N, int K) {
  __shared__ f16 As[128 * 32];
  __shared__ f16 Bs[128 * 32];
  int by = blockIdx.y;
  const f16* A; const f16* Bt; f16* C; int M; int row0;
  if (by < gya) { A = Aa; Bt = Bta; C = Ca; M = Ma; row0 = by * 128; }
  else          { A = Ab; Bt = Btb; C = Cb; M = Mb; row0 = (by - gya) * 128; }
  int tid = threadIdx.x;
  int col0 = blockIdx.x * 128;
  int lane = tid & 63, wv = tid >> 6;
  int wr = (wv & 1) * 64, wc = (wv >> 1) * 64;
  int l16 = lane & 15, q = lane >> 4;
  f32x4 acc[4][4] = {};
  int r = tid >> 2, c8 = (tid & 3) * 8;
  for (int k0 = 0; k0 < K; k0 += 32) {
    int ra = min(row0 + r, M - 1);
    uint4 va = *(const uint4*)&A[(long)ra * K + k0 + c8];
    int ra2 = min(row0 + r + 64, M - 1);
    uint4 va2 = *(const uint4*)&A[(long)ra2 * K + k0 + c8];
    uint4 vb = *(const uint4*)&Bt[(long)(col0 + r) * K + k0 + c8];
    uint4 vb2 = *(const uint4*)&Bt[(long)(col0 + r + 64) * K + k0 + c8];
    *(uint4*)&As[r * 32 + c8] = va;
    *(uint4*)&As[(r + 64) * 32 + c8] = va2;
    *(uint4*)&Bs[r * 32 + c8] = vb;
    *(uint4*)&Bs[(r + 64) * 32 + c8] = vb2;
    __syncthreads();
    f16x8 af[4], bfr[4];
#pragma unroll
    for (int i = 0; i < 4; ++i) {
      af[i] = *(const f16x8*)&As[(wr + i * 16 + l16) * 32 + q * 8];
      bfr[i] = *(const f16x8*)&Bs[(wc + i * 16 + l16) * 32 + q * 8];
    }
#pragma unroll
    for (int i = 0; i < 4; ++i)
#pragma unroll
      for (int j = 0; j < 4; ++j)
        acc[i][j] = __builtin_amdgcn_mfma_f32_16x16x32_f16(af[i], bfr[j], acc[i][j], 0, 0, 0);
    __syncthreads();
  }
#pragma unroll
  for (int i = 0; i < 4; ++i) {
#pragma unroll
    for (int reg = 0; reg < 4; ++reg) {
      int rr = row0 + wr + i * 16 + q * 4 + reg;
      if (rr < M) {
#pragma unroll
        for (int j = 0; j < 4; ++j)
          C[(long)rr * N + col0 + wc + j * 16 + l16] = (f16)acc[i][j][reg];
      }
    }
  }
}

// ---------- layer-0: fp32->f16 convert + el/er via folds; block per node ----------
__global__ __launch_bounds__(256) void eler0_k(
    const float* __restrict__ xu, f16* __restrict__ hbu,
    const float* __restrict__ ef_ui, const float* __restrict__ ef_iu,
    float* __restrict__ el_u, float* __restrict__ er_u,
    const float* __restrict__ xi, f16* __restrict__ hbi,
    float* __restrict__ el_i, float* __restrict__ er_i) {
  const int K = 128;
  __shared__ float xs[128];
  int b = blockIdx.x, t = threadIdx.x;
  const float* x; f16* hb; const float* elf; const float* erf; float* el; float* er; int n;
  if (b < NUSERS) { x = xu; hb = hbu; elf = ef_ui; erf = ef_iu + 4 * K; el = el_u; er = er_u; n = b; }
  else            { x = xi; hb = hbi; elf = ef_iu; erf = ef_ui + 4 * K; el = el_i; er = er_i; n = b - NUSERS; }
  if (t < K) {
    f16 xv = (f16)x[(long)n * K + t];
    hb[(long)n * K + t] = xv;
    xs[t] = (float)xv;
  }
  __syncthreads();
  int j = t >> 5, l = t & 31;
  const float* fr = (j < 4) ? (elf + j * K) : (erf + (j - 4) * K);
  float p = 0.f;
  for (int f = l; f < K; f += 32) p += xs[f] * fr[f];
#pragma unroll
  for (int off = 16; off; off >>= 1) p += __shfl_down(p, off, 32);
  if (l == 0) { if (j < 4) el[n * 4 + j] = p; else er[n * 4 + (j - 4)] = p; }
}

// ---------- CSR build ----------
__global__ void hist_k(const int* __restrict__ ei, int* __restrict__ degi,
                       const int* __restrict__ eu, int* __restrict__ degu) {
  int e = blockIdx.x * blockDim.x + threadIdx.x;
  if (e < NEDGES) atomicAdd(&degi[ei[e]], 1);
  else if (e < 2 * NEDGES) atomicAdd(&degu[eu[e - NEDGES]], 1);
}

__global__ __launch_bounds__(256) void scan1_k(const int* __restrict__ deg,
                                               int* __restrict__ bsum, int N) {
  __shared__ int red[256];
  int base = blockIdx.x * 1024, t = threadIdx.x;
  int s = 0;
#pragma unroll
  for (int j = 0; j < 4; ++j) { int i = base + t * 4 + j; s += (i < N) ? deg[i] : 0; }
  red[t] = s; __syncthreads();
  for (int off = 128; off; off >>= 1) { if (t < off) red[t] += red[t + off]; __syncthreads(); }
  if (t == 0) bsum[blockIdx.x] = red[0];
}

__global__ void scan2_k(int* __restrict__ bsum, int nb, int* __restrict__ endp, int endv) {
  if (threadIdx.x == 0) {
    int run = 0;
    for (int i = 0; i < nb; ++i) { int v = bsum[i]; bsum[i] = run; run += v; }
    *endp = endv;
  }
}

__global__ __launch_bounds__(256) void scan3_k(const int* __restrict__ deg,
                                               const int* __restrict__ bsum,
                                               int* __restrict__ rowptr,
                                               int* __restrict__ cur, int N) {
  __shared__ int tsum[256];
  int base = blockIdx.x * 1024, t = threadIdx.x;
  int v[4]; int s = 0;
#pragma unroll
  for (int j = 0; j < 4; ++j) { int i = base + t * 4 + j; v[j] = (i < N) ? deg[i] : 0; s += v[j]; }
  tsum[t] = s; __syncthreads();
  for (int off = 1; off < 256; off <<= 1) {
    int x = (t >= off) ? tsum[t - off] : 0;
    __syncthreads();
    tsum[t] += x;
    __syncthreads();
  }
  int run = bsum[blockIdx.x] + ((t > 0) ? tsum[t - 1] : 0);
#pragma unroll
  for (int j = 0; j < 4; ++j) {
    int i = base + t * 4 + j;
    if (i < N) { rowptr[i] = run; cur[i] = run; }
    run += v[j];
  }
}

__global__ void scat_k(const int* __restrict__ ei, const int* __restrict__ eu,
                       int* __restrict__ curi, int* __restrict__ srci,
                       int* __restrict__ curu, int* __restrict__ srcu) {
  int e = blockIdx.x * blockDim.x + threadIdx.x;
  if (e < NEDGES) {
    int p = atomicAdd(&curi[ei[e]], 1);
    srci[p] = eu[e];
  } else if (e < 2 * NEDGES) {
    int e2 = e - NEDGES;
    int p = atomicAdd(&curu[eu[e2]], 1);
    srcu[p] = ei[e2];
  }
}

// ---------- fused segment-softmax + gather (+ optional BN-stats); wave per dst ----------
// Side-split grid: blocks [0,gA) -> side A, [gA,..) -> side B; one bns target per block.
// Stats: block LDS reduction over its 4 dst rows, then 512 atomics into a 4-way
// partial-split bns buffer (copy = blockIdx&3) to cut per-address serialization.
template <int W, int DH, typename OUT, bool STATS>
__global__ __launch_bounds__(256) void agg_k(
    const float* __restrict__ elA, const float* __restrict__ erA,
    const int* __restrict__ rpA, const int* __restrict__ srcA,
    const f16* __restrict__ hsA, OUT* __restrict__ outA, int nA, int gA,
    float* __restrict__ bnsA,
    const float* __restrict__ elB, const float* __restrict__ erB,
    const int* __restrict__ rpB, const int* __restrict__ srcB,
    const f16* __restrict__ hsB, OUT* __restrict__ outB, int nB,
    float* __restrict__ bnsB) {
  constexpr int CPL = W >> 6;                   // channels per lane
  constexpr int SHIFT = (W == 256) ? 9 : 8;     // log2(W * sizeof(f16))
  constexpr bool OF16 = (sizeof(OUT) == 2);
  __shared__ float alds[4][256];   // [wave][slot*4 + head]
  __shared__ int soff[4][64];      // [wave][slot] = src row byte offset
  __shared__ float sst[2][256];    // block stats: sum / sumsq per channel
  int tid = threadIdx.x;
  int wv = tid >> 6;
  int lane = tid & 63;
  bool sideA = (blockIdx.x < gA);
  const float* el = sideA ? elA : elB;
  const float* er = sideA ? erA : erB;
  const int* rp   = sideA ? rpA : rpB;
  const int* srcv = sideA ? srcA : srcB;
  const f16* hs   = sideA ? hsA : hsB;
  OUT* outp       = sideA ? outA : outB;
  float* bns      = sideA ? bnsA : bnsB;
  int n           = sideA ? nA : nB;
  int d = (sideA ? blockIdx.x : blockIdx.x - gA) * 4 + wv;
  bool active = (d < n);

  if constexpr (STATS) {
    sst[0][tid] = 0.f; sst[1][tid] = 0.f;
    __syncthreads();
  }

  const float NEG = -3.0e38f;
  float acc[CPL];
#pragma unroll
  for (int q = 0; q < CPL; ++q) acc[q] = 0.f;
  float inv = 0.f;
  int c0 = lane * CPL;
  int h = c0 / DH;
  int s0 = 0, deg = 0;
  if (active) { s0 = rp[d]; deg = rp[d + 1] - s0; }

  if (active && deg > 0) {
    if (deg <= 64) {
      int hh = lane & 3, p = lane >> 2;
      float er_h = er[d * 4 + hh];
      float vv[4];
      float vmax = NEG;
#pragma unroll
      for (int j = 0; j < 4; ++j) {
        int slot = j * 16 + p;
        vv[j] = NEG;
        if (slot < deg) {
          int sj = srcv[s0 + slot];
          if (hh == 0) soff[wv][slot] = sj << SHIFT;
          float v = el[sj * 4 + hh] + er_h;
          v = v > 0.f ? v : 0.2f * v;
          vv[j] = v;
          vmax = fmaxf(vmax, v);
        }
      }
#pragma unroll
      for (int off = 4; off < 64; off <<= 1) vmax = fmaxf(vmax, __shfl_xor(vmax, off, 64));
      float ssum = 0.f;
#pragma unroll
      for (int j = 0; j < 4; ++j) {
        int slot = j * 16 + p;
        if (slot < deg) {
          float e = expf(vv[j] - vmax);
          alds[wv][slot * 4 + hh] = e;
          ssum += e;
        }
      }
#pragma unroll
      for (int off = 4; off < 64; off <<= 1) ssum += __shfl_xor(ssum, off, 64);
      float Sh = __shfl(ssum, (lane & ~3) | h, 64);
      inv = 1.0f / Sh;
      const char* hbase = (const char*)hs + (size_t)c0 * sizeof(f16);
      for (int j = 0; j < deg; ++j) {
        float aj = alds[wv][j * 4 + h];
        int off = soff[wv][j];
        const f16* row = (const f16*)(hbase + (size_t)(unsigned)off);
        if constexpr (CPL == 4) {
          f16x4 hv = *(const f16x4*)row;
          acc[0] += aj * (float)hv[0]; acc[1] += aj * (float)hv[1];
          acc[2] += aj * (float)hv[2]; acc[3] += aj * (float)hv[3];
        } else {
          f16x2 hv = *(const f16x2*)row;
          acc[0] += aj * (float)hv[0]; acc[1] += aj * (float)hv[1];
        }
      }
    } else {
      // ---- generic fallback (deg > 64): strided two-pass + serial gather ----
      float4 er4 = *(const float4*)&er[d * 4];
      float m0 = NEG, m1 = NEG, m2 = NEG, m3 = NEG;
      for (int k = s0 + lane; k < s0 + deg; k += 64) {
        int s = srcv[k];
        float4 e4 = *(const float4*)&el[s * 4];
        float v;
        v = e4.x + er4.x; v = v > 0.f ? v : 0.2f * v; m0 = fmaxf(m0, v);
        v = e4.y + er4.y; v = v > 0.f ? v : 0.2f * v; m1 = fmaxf(m1, v);
        v = e4.z + er4.z; v = v > 0.f ? v : 0.2f * v; m2 = fmaxf(m2, v);
        v = e4.w + er4.w; v = v > 0.f ? v : 0.2f * v; m3 = fmaxf(m3, v);
      }
#pragma unroll
      for (int off = 32; off; off >>= 1) {
        m0 = fmaxf(m0, __shfl_xor(m0, off, 64));
        m1 = fmaxf(m1, __shfl_xor(m1, off, 64));
        m2 = fmaxf(m2, __shfl_xor(m2, off, 64));
        m3 = fmaxf(m3, __shfl_xor(m3, off, 64));
      }
      float S0 = 0.f, S1 = 0.f, S2 = 0.f, S3 = 0.f;
      for (int k = s0 + lane; k < s0 + deg; k += 64) {
        int s = srcv[k];
        float4 e4 = *(const float4*)&el[s * 4];
        float v;
        v = e4.x + er4.x; v = v > 0.f ? v : 0.2f * v; S0 += expf(v - m0);
        v = e4.y + er4.y; v = v > 0.f ? v : 0.2f * v; S1 += expf(v - m1);
        v = e4.z + er4.z; v = v > 0.f ? v : 0.2f * v; S2 += expf(v - m2);
        v = e4.w + er4.w; v = v > 0.f ? v : 0.2f * v; S3 += expf(v - m3);
      }
#pragma unroll
      for (int off = 32; off; off >>= 1) {
        S0 += __shfl_xor(S0, off, 64);
        S1 += __shfl_xor(S1, off, 64);
        S2 += __shfl_xor(S2, off, 64);
        S3 += __shfl_xor(S3, off, 64);
      }
      float mh = h == 0 ? m0 : h == 1 ? m1 : h == 2 ? m2 : m3;
      float Sh = h == 0 ? S0 : h == 1 ? S1 : h == 2 ? S2 : S3;
      float erh = h == 0 ? er4.x : h == 1 ? er4.y : h == 2 ? er4.z : er4.w;
      inv = 1.0f / Sh;
      for (int k = s0; k < s0 + deg; ++k) {
        int s = srcv[k];
        float v = el[s * 4 + h] + erh; v = v > 0.f ? v : 0.2f * v;
        float a = expf(v - mh);
        const f16* row = &hs[(long)s * W + c0];
        if constexpr (CPL == 4) {
          f16x4 hv = *(const f16x4*)row;
          acc[0] += a * (float)hv[0]; acc[1] += a * (float)hv[1];
          acc[2] += a * (float)hv[2]; acc[3] += a * (float)hv[3];
        } else {
          f16x2 hv = *(const f16x2*)row;
          acc[0] += a * (float)hv[0]; acc[1] += a * (float)hv[1];
        }
      }
    }
  }

  // ---- store (+ per-block stats accumulation) ----
  long obase = (long)d * W + c0;
  float vq[CPL];
  if (active) {
    if constexpr (OF16) {
      if constexpr (CPL == 4) {
        f16x4 o;
#pragma unroll
        for (int q = 0; q < 4; ++q) { o[q] = (f16)(acc[q] * inv); vq[q] = (float)o[q]; }
        *(f16x4*)&outp[obase] = o;
      } else {
        f16x2 o;
#pragma unroll
        for (int q = 0; q < 2; ++q) { o[q] = (f16)(acc[q] * inv); vq[q] = (float)o[q]; }
        *(f16x2*)&outp[obase] = o;
      }
    } else {
      if constexpr (CPL == 4) {
        *(float4*)&outp[obase] = make_float4(acc[0] * inv, acc[1] * inv, acc[2] * inv, acc[3] * inv);
      } else {
        *(float2*)&outp[obase] = make_float2(acc[0] * inv, acc[1] * inv);
      }
    }
  }
  if constexpr (STATS) {
    if (active) {
#pragma unroll
      for (int q = 0; q < CPL; ++q) {
        atomicAdd(&sst[0][c0 + q], vq[q]);
        atomicAdd(&sst[1][c0 + q], vq[q] * vq[q]);
      }
    }
    __syncthreads();
    float* b = bns + (blockIdx.x & 3) * 512;
    atomicAdd(&b[tid], sst[0][tid]);
    atomicAdd(&b[256 + tid], sst[1][tid]);
  }
}

// ---------- fused BN apply + activation -> f16 AND next-layer el/er; block per row ----------
// sums: 4 partial copies of [sum(256) | sumsq(256)], stride 512.
__global__ __launch_bounds__(256) void bn_fused_k(
    const f16* __restrict__ xu, const float* __restrict__ su, const float* __restrict__ gbu,
    f16* __restrict__ yu, int Nu,
    const f16* __restrict__ xi, const float* __restrict__ si, const float* __restrict__ gbi,
    f16* __restrict__ yi, int Ni,
    const float* __restrict__ efu, const float* __restrict__ efiu,   // next-layer folds, K=256
    float* __restrict__ el_u, float* __restrict__ er_u,
    float* __restrict__ el_i, float* __restrict__ er_i, int act) {
  const int Kn = 256;
  __shared__ float xs[256];
  int b = blockIdx.x, t = threadIdx.x;
  const f16* x; const float* sums; const float* gb; f16* y; int n; int N;
  const float* elf; const float* erf; float* el; float* er;
  if (b < Nu) { x = xu; sums = su; gb = gbu; y = yu; n = b; N = Nu; elf = efu;  erf = efiu + 4 * Kn; el = el_u; er = er_u; }
  else        { x = xi; sums = si; gb = gbi; y = yi; n = b - Nu; N = Ni; elf = efiu; erf = efu + 4 * Kn;  el = el_i; er = er_i; }
  long base = (long)n * 256;
  float val = (float)x[base + t];
  float inv_n = 1.0f / (float)N;
  float s  = sums[t] + sums[512 + t] + sums[1024 + t] + sums[1536 + t];
  float s2 = sums[256 + t] + sums[768 + t] + sums[1280 + t] + sums[1792 + t];
  float mean = s * inv_n;
  float var = s2 * inv_n - mean * mean;
  float v = gb[t] * (val - mean) * rsqrtf(var + 1e-5f) + gb[256 + t];
  v = act ? tanhf(v) : (v > 0.f ? v : 0.01f * v);
  y[base + t] = (f16)v;
  xs[t] = v;
  __syncthreads();
  int j = t >> 5, l = t & 31;
  const float* fr = (j < 4) ? (elf + j * Kn) : (erf + (j - 4) * Kn);
  float p = 0.f;
  for (int f = l; f < Kn; f += 32) p += xs[f] * fr[f];
#pragma unroll
  for (int off = 16; off; off >>= 1) p += __shfl_down(p, off, 32);
  if (l == 0) { if (j < 4) el[n * 4 + j] = p; else er[n * 4 + (j - 4)] = p; }
}

extern "C" void kernel_launch(void* const* d_in, const int* in_sizes, int n_in,
                              void* d_out, int out_size, void* d_ws, size_t ws_size,
                              hipStream_t stream) {
  const float* x_user = (const float*)d_in[0];
  const float* x_item = (const float*)d_in[1];
  const int* eu = (const int*)d_in[2];
  const int* ei = (const int*)d_in[3];
  const float *Wm[4][2], *Am[4][2];
  for (int L = 0; L < 4; ++L) {
    Wm[L][0] = (const float*)d_in[4 + L * 4 + 0];
    Am[L][0] = (const float*)d_in[4 + L * 4 + 1];
    Wm[L][1] = (const float*)d_in[4 + L * 4 + 2];
    Am[L][1] = (const float*)d_in[4 + L * 4 + 3];
  }
  const float* bnu = (const float*)d_in[20];
  const float* bni = (const float*)d_in[21];
  float* out = (float*)d_out;

  float* ws = (float*)d_ws;
  size_t o = 0;
  // ---- zeroed-together region: deg_i | deg_u | bns_all (one memset covers all) ----
  int* deg_i    = (int*)(ws + o); o += NITEMS;
  int* deg_u    = (int*)(ws + o); o += NUSERS;
  float* bns_all = ws + o; o += 3 * 2 * 2048;   // [layer][side(0=items,1=users)][4 copies x 512]
  // ----
  float* el_u = ws + o; o += (size_t)NUSERS * 4;
  float* er_u = ws + o; o += (size_t)NUSERS * 4;
  float* el_i = ws + o; o += (size_t)NITEMS * 4;
  float* er_i = ws + o; o += (size_t)NITEMS * 4;
  float* ef_all[4][2];
  for (int L = 0; L < 4; ++L)
    for (int rl = 0; rl < 2; ++rl) { ef_all[L][rl] = ws + o; o += 2048; }
  // f16 buffers (offsets in float units; all 16B aligned)
  f16* hb_u   = (f16*)(ws + o); o += (size_t)NUSERS * 128;
  f16* hb_i   = (f16*)(ws + o); o += (size_t)NITEMS * 128;
  f16* hsb_u  = (f16*)(ws + o); o += (size_t)NUSERS * 128;
  f16* hsb_i  = (f16*)(ws + o); o += (size_t)NITEMS * 128;
  f16* aggh_u = (f16*)(ws + o); o += (size_t)NUSERS * 128;
  f16* aggh_i = (f16*)(ws + o); o += (size_t)NITEMS * 128;
  f16* Bt_all[4][2];
  for (int L = 0; L < 4; ++L) {
    int K = (L == 0) ? 128 : 256;
    int W = (L == 3) ? 128 : 256;
    for (int rl = 0; rl < 2; ++rl) { Bt_all[L][rl] = (f16*)(ws + o); o += (size_t)K * W / 2; }
  }
  int* rowptr_i = (int*)(ws + o); o += NITEMS + 1;
  int* rowptr_u = (int*)(ws + o); o += NUSERS + 1;
  int* cur_i    = (int*)(ws + o); o += NITEMS;
  int* cur_u    = (int*)(ws + o); o += NUSERS;
  int* bsum     = (int*)(ws + o); o += 256;
  int* csrsrc_i = (int*)(ws + o); o += NEDGES;
  int* csrsrc_u = (int*)(ws + o); o += NEDGES;

  const int gE2 = (2 * NEDGES + 255) / 256;
  const int nb_i = (NITEMS + 1023) / 1024;
  const int nb_u = (NUSERS + 1023) / 1024;

  // ---- CSR build + bns zero (edges identical across layers) ----
  hipMemsetAsync(deg_i, 0, (NITEMS + NUSERS + 3 * 2 * 2048) * sizeof(int), stream);
  hist_k<<<dim3(gE2), dim3(256), 0, stream>>>(ei, deg_i, eu, deg_u);
  scan1_k<<<dim3(nb_i), dim3(256), 0, stream>>>(deg_i, bsum, NITEMS);
  scan2_k<<<dim3(1), dim3(64), 0, stream>>>(bsum, nb_i, rowptr_i + NITEMS, NEDGES);
  scan3_k<<<dim3(nb_i), dim3(256), 0, stream>>>(deg_i, bsum, rowptr_i, cur_i, NITEMS);
  scan1_k<<<dim3(nb_u), dim3(256), 0, stream>>>(deg_u, bsum, NUSERS);
  scan2_k<<<dim3(1), dim3(64), 0, stream>>>(bsum, nb_u, rowptr_u + NUSERS, NEDGES);
  scan3_k<<<dim3(nb_u), dim3(256), 0, stream>>>(deg_u, bsum, rowptr_u, cur_u, NUSERS);
  scat_k<<<dim3(gE2), dim3(256), 0, stream>>>(ei, eu, cur_i, csrsrc_i, cur_u, csrsrc_u);

  // ---- all layer preps upfront (Bt + el/er folds) ----
  for (int L = 0; L < 4; ++L) {
    int K = (L == 0) ? 128 : 256;
    int dh = (L == 3) ? 32 : 64;
    int W = 4 * dh;
    prep_k<<<dim3((2 * K * W + 255) / 256), dim3(256), 0, stream>>>(
        Wm[L][0], Am[L][0], Bt_all[L][0], ef_all[L][0],
        Wm[L][1], Am[L][1], Bt_all[L][1], ef_all[L][1], K, W, dh);
  }

  // layer-0: convert fp32 -> f16 AND compute el/er in one pass
  eler0_k<<<dim3(NUSERS + NITEMS), dim3(256), 0, stream>>>(
      x_user, hb_u, ef_all[0][0], ef_all[0][1], el_u, er_u,
      x_item, hb_i, el_i, er_i);

  int K = 128;
  const int gAi = (NITEMS + 3) / 4, gAu = (NUSERS + 3) / 4;
  for (int L = 0; L < 4; ++L) {
    const int dh = (L == 3) ? 32 : 64;
    const int W = 4 * dh;

    const int gya = (NUSERS + 127) / 128, gyb = (NITEMS + 127) / 128;
    hgemm2_k<<<dim3(W / 128, gya + gyb), dim3(256), 0, stream>>>(
        hb_u, Bt_all[L][0], hsb_u, NUSERS, gya, hb_i, Bt_all[L][1], hsb_i, NITEMS, W, K);

    if (L < 3) {
      float* bns_i_L = bns_all + (L * 2 + 0) * 2048;
      float* bns_u_L = bns_all + (L * 2 + 1) * 2048;
      agg_k<256, 64, f16, true><<<dim3(gAi + gAu), dim3(256), 0, stream>>>(
          el_u, er_i, rowptr_i, csrsrc_i, hsb_u, aggh_i, NITEMS, gAi, bns_i_L,
          el_i, er_u, rowptr_u, csrsrc_u, hsb_i, aggh_u, NUSERS, bns_u_L);
      bn_fused_k<<<dim3(NUSERS + NITEMS), dim3(256), 0, stream>>>(
          aggh_u, bns_u_L, bnu + L * 512, hb_u, NUSERS,
          aggh_i, bns_i_L, bni + L * 512, hb_i, NITEMS,
          ef_all[L + 1][0], ef_all[L + 1][1],
          el_u, er_u, el_i, er_i, L == 2);
      K = 256;
    } else {
      agg_k<128, 32, float, false><<<dim3(gAi + gAu), dim3(256), 0, stream>>>(
          el_u, er_i, rowptr_i, csrsrc_i, hsb_u, out + (size_t)NUSERS * 128, NITEMS, gAi, nullptr,
          el_i, er_u, rowptr_u, csrsrc_u, hsb_i, out, NUSERS, nullptr);
    }
  }
}